// Round 1
// 192.840 us; speedup vs baseline: 1.0066x; 1.0066x over previous
//
#include <hip/hip_runtime.h>

#define NN 10000
#define EE 160000
#define ETOT (EE + NN)
#define EMB 768
#define ODIM 1024
#define NEG 0.2f
#define CAP 56          // max in/out degree ~45 (Binom(160k,1e-4) max + self-loop)

// ---- workspace layout (4B units) ----
#define OFF_P      0          // 12288 : P precontract [k*16+j] (src j<8, dst j>=8)
#define OFF_Q      12288      // 8
#define OFF_EAACC  12296      // 1 (zeroed)
#define OFF_CNTD   12304      // int[10000] (zeroed)
#define OFF_CNTS   22304      // int[10000] (zeroed)
#define ZERO_START 12296
#define ZERO_CNT   20008
#define OFF_A      32304      // 10000*16 : a_src(0..7), a_dst(8..15)
#define OFF_SRCD   192304     // int[10000*CAP] : src per dst-bucket slot
#define OFF_AED    752304     // float[10000*CAP] : edge_attr per dst slot (marker=self)
#define OFF_DSTS   1312304    // int[10000*CAP] : dst per src-bucket slot
#define OFF_AES    1872304    // float[10000*CAP] : edge_attr per src slot
#define OFF_RDEN   2432304    // 80000 : 1/denominator per (dst,h)
#define OFF_Z      2512304    // 2*8*768
#define OFF_YPART  2524592    // 157*6144 : y partials [b][h*768+col]
// end 3489200 floats = 14.0 MB

#define SELF_MARK 3.0e38f

// K1F: P/Q precontract + bias-dot + edge_attr sum + bucket fill (block roles)
__global__ __launch_bounds__(256) void k1f(
    const float* __restrict__ W, const float* __restrict__ att_src,
    const float* __restrict__ att_dst, const float* __restrict__ W_edge,
    const float* __restrict__ att_edge, const float* __restrict__ edge_attr,
    const float* __restrict__ bias, const float* __restrict__ clf_W,
    const float* __restrict__ clf_b, float* __restrict__ out,
    const int* __restrict__ ei, float* __restrict__ ws) {
  int b = blockIdx.x;
  if (b < 48) {
    int tid = b * 256 + threadIdx.x;   // 0..12287
    int k = tid >> 4, j = tid & 15, h = j & 7;
    const float* att = (j < 8) ? att_src : att_dst;
    const float4* wp = (const float4*)(W + k * ODIM + h * 128);
    const float4* ap = (const float4*)(att + h * 128);
    float acc = 0.f;
    #pragma unroll 8
    for (int c = 0; c < 32; ++c) {
      float4 w4 = wp[c], a4 = ap[c];
      acc += w4.x * a4.x + w4.y * a4.y + w4.z * a4.z + w4.w * a4.w;
    }
    ws[OFF_P + k * 16 + j] = acc;
  } else if (b == 48) {
    if (threadIdx.x < 8) {
      int h = threadIdx.x;
      float acc = 0.f;
      #pragma unroll 8
      for (int c = 0; c < 128; ++c) acc += W_edge[h * 128 + c] * att_edge[h * 128 + c];
      ws[OFF_Q + h] = acc;
    }
  } else if (b == 49) {
    // bias contribution: out = clf_b + sum_i bias[i&1023]*clf_W[i]
    __shared__ float red[8];
    int t = threadIdx.x;
    float b0 = 0.f, b1 = 0.f;
    for (int i = t; i < 3072; i += 256) {
      float f = bias[i & 1023];
      b0 += f * clf_W[2 * i];
      b1 += f * clf_W[2 * i + 1];
    }
    #pragma unroll
    for (int o = 32; o > 0; o >>= 1) {
      b0 += __shfl_down(b0, o, 64);
      b1 += __shfl_down(b1, o, 64);
    }
    if ((t & 63) == 0) { red[(t >> 6) * 2] = b0; red[(t >> 6) * 2 + 1] = b1; }
    __syncthreads();
    if (t == 0) {
      out[0] = clf_b[0] + red[0] + red[2] + red[4] + red[6];
      out[1] = clf_b[1] + red[1] + red[3] + red[5] + red[7];
    }
  } else if (b < 114) {
    int bi = b - 50;   // 64 blocks: sum edge_attr
    float acc = 0.f;
    for (int i = bi * 256 + threadIdx.x; i < EE; i += 64 * 256) acc += edge_attr[i];
    #pragma unroll
    for (int off = 32; off > 0; off >>= 1) acc += __shfl_down(acc, off, 64);
    if ((threadIdx.x & 63) == 0) atomicAdd(&ws[OFF_EAACC], acc);
  } else {
    int e = (b - 114) * 256 + threadIdx.x;
    if (e >= ETOT) return;
    int src, dst; float ea;
    if (e < EE) { src = ei[e]; dst = ei[EE + e]; ea = edge_attr[e]; }
    else { src = dst = e - EE; ea = SELF_MARK; }
    int* cntd = (int*)(ws + OFF_CNTD);
    int* cnts = (int*)(ws + OFF_CNTS);
    int pd = atomicAdd(&cntd[dst], 1);
    if (pd < CAP) {
      ((int*)(ws + OFF_SRCD))[dst * CAP + pd] = src;
      ws[OFF_AED + dst * CAP + pd] = ea;
    }
    int ps = atomicAdd(&cnts[src], 1);
    if (ps < CAP) {
      ((int*)(ws + OFF_DSTS))[src * CAP + ps] = dst;
      ws[OFF_AES + src * CAP + ps] = ea;
    }
  }
}

// KAX: A = x @ P, full P in 48KB LDS (3 blocks/CU), in-LDS reduction
__global__ __launch_bounds__(256) void kAx(const float* __restrict__ x,
                                           float* __restrict__ ws) {
  __shared__ float smem[12288];
  for (int i = threadIdx.x; i < 3072; i += 256)
    ((float4*)smem)[i] = ((const float4*)(ws + OFF_P))[i];
  __syncthreads();
  int nl = threadIdx.x & 31, cg = threadIdx.x >> 5;   // cg in [0,8): 96-col group
  int n = blockIdx.x * 32 + nl;
  float a[16];
  #pragma unroll
  for (int j = 0; j < 16; ++j) a[j] = 0.f;
  if (n < NN) {
    const float4* xr = (const float4*)(x + n * EMB + cg * 96);
    for (int kk = 0; kk < 24; ++kk) {
      float4 xv = xr[kk];
      const float* pr = &smem[(cg * 96 + kk * 4) * 16];
      #pragma unroll
      for (int j = 0; j < 16; ++j) a[j] += xv.x * pr[j];
      #pragma unroll
      for (int j = 0; j < 16; ++j) a[j] += xv.y * pr[16 + j];
      #pragma unroll
      for (int j = 0; j < 16; ++j) a[j] += xv.z * pr[32 + j];
      #pragma unroll
      for (int j = 0; j < 16; ++j) a[j] += xv.w * pr[48 + j];
    }
  }
  __syncthreads();   // all P reads done; reuse smem for partials
  #pragma unroll
  for (int j = 0; j < 16; ++j) smem[(cg * 16 + j) * 33 + nl] = a[j];
  __syncthreads();
  for (int w = threadIdx.x; w < 512; w += 256) {
    int rnl = w >> 4, j = w & 15;
    int nn = blockIdx.x * 32 + rnl;
    if (nn < NN) {
      float s = 0.f;
      #pragma unroll
      for (int c2 = 0; c2 < 8; ++c2) s += smem[(c2 * 16 + j) * 33 + rnl];
      ws[OFF_A + nn * 16 + j] = s;
    }
  }
}

// KD: rden per (dst,h), exp recomputed from A-table gathers (L2-resident)
__global__ __launch_bounds__(128) void kD(float* __restrict__ ws) {
  int t = blockIdx.x * 128 + threadIdx.x;   // 0..79999
  int dst = t >> 3, h = t & 7;
  int deg = ((const int*)(ws + OFF_CNTD))[dst];
  if (deg > CAP) deg = CAP;
  float adh = ws[OFF_A + dst * 16 + 8 + h];
  float qh = ws[OFF_Q + h];
  float mean = ws[OFF_EAACC] * (1.0f / EE);
  const int* srow = (const int*)(ws + OFF_SRCD) + dst * CAP;
  const float* aerow = ws + OFF_AED + dst * CAP;
  float den = 0.f;
  for (int j = 0; j < deg; ++j) {
    float ae = aerow[j];
    if (ae > 1e37f) ae = mean;
    float v = ws[OFF_A + srow[j] * 16 + h] + adh + ae * qh;
    v = (v >= 0.f) ? v : NEG * v;
    den += __expf(v);
  }
  ws[OFF_RDEN + t] = 1.0f / den;
}

// KSYZ: blocks 0..470: fused s-compute (in LDS, 3x redundant) + y-partials;
//       blocks 471..476: z for text/image (exp recomputed)
__global__ __launch_bounds__(256) void kSYZ(const float* __restrict__ x,
                                            const int* __restrict__ tptr,
                                            const int* __restrict__ iptr,
                                            float* __restrict__ ws) {
  __shared__ float sL[512];
  __shared__ int srcS[CAP];
  float mean = ws[OFF_EAACC] * (1.0f / EE);
  if (blockIdx.x < 471) {
    int bx = blockIdx.x / 3, c = blockIdx.x % 3;
    int base = bx * 64;
    // step 1: s[node][h] for this 64-node window (each thread 2 tasks)
    for (int t = threadIdx.x; t < 512; t += 256) {
      int n = base + (t >> 3), h = t & 7;
      float s = 0.f;
      if (n < NN) {
        int deg = ((const int*)(ws + OFF_CNTS))[n];
        if (deg > CAP) deg = CAP;
        float ash = ws[OFF_A + n * 16 + h];
        float qh = ws[OFF_Q + h];
        const int* drow = (const int*)(ws + OFF_DSTS) + n * CAP;
        const float* aerow = ws + OFF_AES + n * CAP;
        for (int j = 0; j < deg; ++j) {
          int dd = drow[j];
          float ae = aerow[j];
          if (ae > 1e37f) ae = mean;
          float v = ash + ws[OFF_A + dd * 16 + 8 + h] + ae * qh;
          v = (v >= 0.f) ? v : NEG * v;
          s += __expf(v) * ws[OFF_RDEN + dd * 8 + h];
        }
      }
      sL[t] = s;
    }
    __syncthreads();
    // step 2: y-partials over this window's 256-col chunk
    int col = c * 256 + threadIdx.x;
    float acc[8];
    #pragma unroll
    for (int h = 0; h < 8; ++h) acc[h] = 0.f;
    int nmax = (NN - base < 64) ? (NN - base) : 64;
    for (int i = 0; i < nmax; ++i) {
      float xv = x[(base + i) * EMB + col];
      const float* sv = &sL[i * 8];
      #pragma unroll
      for (int h = 0; h < 8; ++h) acc[h] += xv * sv[h];
    }
    float* yp = ws + OFF_YPART + bx * 6144 + col;
    #pragma unroll
    for (int h = 0; h < 8; ++h) yp[h * 768] = acc[h];
  } else {
    int r = blockIdx.x - 471;       // 0..5
    int d = r / 3, kc = r % 3;      // d: 0=text 1=image; kc: 256-col chunk
    int target = (d == 0) ? tptr[0] : iptr[0];
    int deg = ((const int*)(ws + OFF_CNTD))[target];
    if (deg > CAP) deg = CAP;
    for (int idx = threadIdx.x; idx < deg * 8; idx += 256) {
      int j = idx >> 3, h = idx & 7;
      int srcj = ((const int*)(ws + OFF_SRCD))[target * CAP + j];
      float ae = ws[OFF_AED + target * CAP + j];
      if (ae > 1e37f) ae = mean;
      float v = ws[OFF_A + srcj * 16 + h] + ws[OFF_A + target * 16 + 8 + h]
              + ae * ws[OFF_Q + h];
      v = (v >= 0.f) ? v : NEG * v;
      sL[idx] = __expf(v) * ws[OFF_RDEN + target * 8 + h];
      if (h == 0) srcS[j] = srcj;
    }
    __syncthreads();
    int col = kc * 256 + threadIdx.x;
    float acc[8];
    #pragma unroll
    for (int h = 0; h < 8; ++h) acc[h] = 0.f;
    for (int j = 0; j < deg; ++j) {
      float xv = x[srcS[j] * EMB + col];
      const float* wv = &sL[j * 8];
      #pragma unroll
      for (int h = 0; h < 8; ++h) acc[h] += wv[h] * xv;
    }
    #pragma unroll
    for (int h = 0; h < 8; ++h) ws[OFF_Z + (d * 8 + h) * EMB + col] = acc[h];
  }
}

// K8: Y-reduce + projection + classifier dot -> atomicAdd into out
__global__ __launch_bounds__(128) void k8(const float* __restrict__ W,
                                          const float* __restrict__ clf_W,
                                          float* __restrict__ out,
                                          float* __restrict__ ws) {
  __shared__ float vL[144];
  __shared__ float red[4];
  int h = blockIdx.x, kc = blockIdx.y, kbase = kc * 48;
  for (int i = threadIdx.x; i < 144; i += 128) {
    int d = i / 48, k = i - d * 48;
    float v;
    if (d == 0) {
      float acc = 0.f;
      for (int b = 0; b < 157; ++b)
        acc += ws[OFF_YPART + b * 6144 + h * 768 + kbase + k];
      v = acc * (1.0f / NN);
    } else {
      v = ws[OFF_Z + ((d - 1) * 8 + h) * 768 + kbase + k];
    }
    vL[i] = v;
  }
  __syncthreads();
  int c = threadIdx.x;
  float a0 = 0.f, a1 = 0.f, a2 = 0.f;
  #pragma unroll 4
  for (int k = 0; k < 48; ++k) {
    float wv = W[(kbase + k) * ODIM + h * 128 + c];
    a0 += vL[k] * wv;
    a1 += vL[48 + k] * wv;
    a2 += vL[96 + k] * wv;
  }
  int ib = h * 128 + c;
  float l0 = a0 * clf_W[2 * ib] + a1 * clf_W[2 * (1024 + ib)]
           + a2 * clf_W[2 * (2048 + ib)];
  float l1 = a0 * clf_W[2 * ib + 1] + a1 * clf_W[2 * (1024 + ib) + 1]
           + a2 * clf_W[2 * (2048 + ib) + 1];
  #pragma unroll
  for (int o = 32; o > 0; o >>= 1) {
    l0 += __shfl_down(l0, o, 64);
    l1 += __shfl_down(l1, o, 64);
  }
  if ((threadIdx.x & 63) == 0) {
    red[(threadIdx.x >> 6) * 2] = l0;
    red[(threadIdx.x >> 6) * 2 + 1] = l1;
  }
  __syncthreads();
  if (threadIdx.x == 0) {
    atomicAdd(&out[0], red[0] + red[2]);
    atomicAdd(&out[1], red[1] + red[3]);
  }
}

extern "C" void kernel_launch(void* const* d_in, const int* in_sizes, int n_in,
                              void* d_out, int out_size, void* d_ws, size_t ws_size,
                              hipStream_t stream) {
  const float* x        = (const float*)d_in[0];
  const int*   ei       = (const int*)d_in[1];
  const float* edge_attr= (const float*)d_in[2];
  const int*   tptr     = (const int*)d_in[3];
  const int*   iptr     = (const int*)d_in[4];
  const float* W        = (const float*)d_in[5];
  const float* att_src  = (const float*)d_in[6];
  const float* att_dst  = (const float*)d_in[7];
  const float* W_edge   = (const float*)d_in[8];
  const float* att_edge = (const float*)d_in[9];
  const float* bias     = (const float*)d_in[10];
  const float* clf_W    = (const float*)d_in[11];
  const float* clf_b    = (const float*)d_in[12];
  float* ws  = (float*)d_ws;
  float* out = (float*)d_out;

  hipMemsetAsync(ws + ZERO_START, 0, ZERO_CNT * sizeof(float), stream);
  k1f<<<779, 256, 0, stream>>>(W, att_src, att_dst, W_edge, att_edge, edge_attr,
                               bias, clf_W, clf_b, out, ei, ws);
  kAx<<<313, 256, 0, stream>>>(x, ws);
  kD<<<625, 128, 0, stream>>>(ws);
  kSYZ<<<477, 256, 0, stream>>>(x, tptr, iptr, ws);
  dim3 g8(8, 16);
  k8<<<g8, 128, 0, stream>>>(W, clf_W, out, ws);
}